// Round 1
// baseline (292.028 us; speedup 1.0000x reference)
//
#include <hip/hip_runtime.h>
#include <cstdint>

// Fused butterfly-GLU-butterfly.
// Rows: BT = 16384, layer1: S=4 stacks, n=1024, 10 stages; GLU; layer2: n=2048, 11 stages.
// One block = 8 rows (2 "quads" of 4 rows). LDS element = float4 = 4 rows' values at one
// butterfly position -> every LDS access is ds_*_b128. XOR swizzle e^((e>>4)&7) kills the
// power-of-2 stride bank conflicts. Twiddles live in VGPRs, reused across the block's rows.

#define NTHR 512
#define NBLK 2048   // 2048 * 8 rows = 16384

__device__ __forceinline__ float sigmf(float g) {
    return __builtin_amdgcn_rcpf(1.0f + __expf(-g));
}

// butterfly pair-op on 4 packed rows: a' = t00*a + t01*b ; b' = t10*a + t11*b
// t = (t00,t01,t10,t11) from twiddle[...][2][2] row-major
__device__ __forceinline__ void bfly(float4& a, float4& b, const float4 t) {
    float4 n0, n1;
    n0.x = fmaf(t.x, a.x, t.y * b.x);
    n0.y = fmaf(t.x, a.y, t.y * b.y);
    n0.z = fmaf(t.x, a.z, t.y * b.z);
    n0.w = fmaf(t.x, a.w, t.y * b.w);
    n1.x = fmaf(t.z, a.x, t.w * b.x);
    n1.y = fmaf(t.z, a.y, t.w * b.y);
    n1.z = fmaf(t.z, a.z, t.w * b.z);
    n1.w = fmaf(t.z, a.w, t.w * b.w);
    a = n0; b = n1;
}

__global__ __launch_bounds__(NTHR, 2) void glu_butterfly(
    const float* __restrict__ x, const float* __restrict__ tw1,
    const float* __restrict__ b1, const float* __restrict__ tw2,
    const float* __restrict__ b2, float* __restrict__ out)
{
    extern __shared__ float4 lds[];   // 2 quads * 4096 float4 = 131072 B
    const int t    = threadIdx.x;
    const int row0 = blockIdx.x * 8;  // 8 rows per block
    const float4* tw1q = (const float4*)tw1;  // (4,10,512,2,2) -> f4 idx (s*10+j)*512 + tidx
    const float4* tw2q = (const float4*)tw2;  // (1,11,1024,2,2) -> f4 idx j*1024 + tidx

    // ================= L1P1: global x -> stages 0..3 (strides 1,2,4,8) -> LDS ============
    {
        const int q   = t >> 8;        // quad 0/1 (rows q*4 .. q*4+3)
        const int pos = t & 255;
        const int s   = pos >> 6;      // stack
        const int c   = pos & 63;      // 16-element chunk within stack
        float4 d[16];
        float* dp = (float*)d;
        const float* xb = x + (size_t)(row0 + q*4) * 1024 + c*16;
        #pragma unroll
        for (int rr = 0; rr < 4; ++rr) {            // 4 rows of the quad
            const float4* xp = (const float4*)(xb + rr*1024);
            #pragma unroll
            for (int kk = 0; kk < 4; ++kk) {
                float4 v = xp[kk];
                dp[(kk*4+0)*4+rr] = v.x;
                dp[(kk*4+1)*4+rr] = v.y;
                dp[(kk*4+2)*4+rr] = v.z;
                dp[(kk*4+3)*4+rr] = v.w;
            }
        }
        #pragma unroll
        for (int j = 0; j < 4; ++j) {
            const float4* tq = tw1q + (s*10 + j)*512 + c*8;   // tidx = c*8 + m
            #pragma unroll
            for (int m = 0; m < 8; ++m) {
                const int i0 = ((m >> j) << (j+1)) | (m & ((1<<j)-1));
                const int i1 = i0 | (1 << j);
                bfly(d[i0], d[i1], tq[m]);
            }
        }
        const int ebase = s*1024 + c*16;
        const int sw    = (ebase >> 4) & 7;
        float4* lq = lds + q*4096;
        #pragma unroll
        for (int k = 0; k < 16; ++k)
            lq[(ebase + k) ^ sw] = d[k];
    }
    __syncthreads();

    // ================= L1P2: stages 4..6 (strides 16,32,64) ==============================
    {
        const int s = t >> 7;
        const int b = t & 127;
        const int ebase = s*1024 + (b & 15) + ((b >> 4) << 7);  // p = (b&15)|(r<<4)|((b>>4)<<7)
        float4 tws[3][4];
        #pragma unroll
        for (int jj = 0; jj < 3; ++jj) {
            // tidx = (b&15) + m*16 + (b>>4)*64
            const float4* tq = tw1q + (s*10 + 4 + jj)*512 + (b & 15) + ((b >> 4) << 6);
            #pragma unroll
            for (int m = 0; m < 4; ++m) tws[jj][m] = tq[m << 4];
        }
        #pragma unroll
        for (int q = 0; q < 2; ++q) {
            float4* lq = lds + q*4096;
            float4 v[8];
            #pragma unroll
            for (int r = 0; r < 8; ++r) v[r] = lq[(ebase + (r<<4)) ^ r];   // (e>>4)&7 == r
            #pragma unroll
            for (int jj = 0; jj < 3; ++jj) {
                #pragma unroll
                for (int m = 0; m < 4; ++m) {
                    const int r0 = ((m >> jj) << (jj+1)) | (m & ((1<<jj)-1));
                    const int r1 = r0 | (1 << jj);
                    bfly(v[r0], v[r1], tws[jj][m]);
                }
            }
            #pragma unroll
            for (int r = 0; r < 8; ++r) lq[(ebase + (r<<4)) ^ r] = v[r];
        }
    }
    __syncthreads();

    // ================= L1P3: stages 7..9 (strides 128,256,512) + bias b1 =================
    {
        const int s = t >> 7;
        const int b = t & 127;
        const int ebase = s*1024 + b;        // p = (b&127) | (r<<7)
        const int sw    = (b >> 4) & 7;
        float4 tws[3][4];
        #pragma unroll
        for (int jj = 0; jj < 3; ++jj) {
            const float4* tq = tw1q + (s*10 + 7 + jj)*512 + b;  // tidx = b + m*128
            #pragma unroll
            for (int m = 0; m < 4; ++m) tws[jj][m] = tq[m << 7];
        }
        float bias[8];
        #pragma unroll
        for (int r = 0; r < 8; ++r) bias[r] = b1[s*1024 + b + (r<<7)];
        #pragma unroll
        for (int q = 0; q < 2; ++q) {
            float4* lq = lds + q*4096;
            float4 v[8];
            #pragma unroll
            for (int r = 0; r < 8; ++r) v[r] = lq[(ebase + (r<<7)) ^ sw];
            #pragma unroll
            for (int jj = 0; jj < 3; ++jj) {
                #pragma unroll
                for (int m = 0; m < 4; ++m) {
                    const int r0 = ((m >> jj) << (jj+1)) | (m & ((1<<jj)-1));
                    const int r1 = r0 | (1 << jj);
                    bfly(v[r0], v[r1], tws[jj][m]);
                }
            }
            #pragma unroll
            for (int r = 0; r < 8; ++r) {
                v[r].x += bias[r]; v[r].y += bias[r]; v[r].z += bias[r]; v[r].w += bias[r];
                lq[(ebase + (r<<7)) ^ sw] = v[r];
            }
        }
    }
    __syncthreads();

    // ================= L2P1: GLU (a*sigmoid(gates)) + layer2 stages 0..3 =================
    // u lives at positions 0..2047 (stacks 0,1); gates at 2048..4095. Output -> ping [2048,4096).
    if (t < 256) {
        const int q   = t >> 7;
        const int pos = t & 127;
        const int sw  = pos & 7;
        float4* lq = lds + q*4096;
        float4 u[16];
        #pragma unroll
        for (int k = 0; k < 16; ++k) {
            const int e = pos*16 + k;
            float4 a = lq[e ^ sw];
            float4 g = lq[(e + 2048) ^ sw];
            u[k].x = a.x * sigmf(g.x);
            u[k].y = a.y * sigmf(g.y);
            u[k].z = a.z * sigmf(g.z);
            u[k].w = a.w * sigmf(g.w);
        }
        #pragma unroll
        for (int j = 0; j < 4; ++j) {
            const float4* tq = tw2q + j*1024 + pos*8;   // tidx = pos*8 + m
            #pragma unroll
            for (int m = 0; m < 8; ++m) {
                const int i0 = ((m >> j) << (j+1)) | (m & ((1<<j)-1));
                const int i1 = i0 | (1 << j);
                bfly(u[i0], u[i1], tq[m]);
            }
        }
        #pragma unroll
        for (int k = 0; k < 16; ++k)
            lq[(pos*16 + k + 2048) ^ sw] = u[k];
    }
    __syncthreads();

    // ================= L2P2: stages 4..7 (strides 16..128), ping -> pong [0,2048) =========
    if (t < 256) {
        const int q = t >> 7;
        const int b = t & 127;
        const int ebase = (b & 15) + ((b >> 4) << 8);   // p = (b&15)|(r<<4)|((b>>4)<<8)
        float4* lq = lds + q*4096;
        float4 v[16];
        #pragma unroll
        for (int r = 0; r < 16; ++r)
            v[r] = lq[(2048 + ebase + (r << 4)) ^ (r & 7)];
        #pragma unroll
        for (int jj = 0; jj < 4; ++jj) {
            // tidx = (b&15) + m*16 + (b>>4)*128
            const float4* tq = tw2q + (4+jj)*1024 + (b & 15) + ((b >> 4) << 7);
            #pragma unroll
            for (int m = 0; m < 8; ++m) {
                const int r0 = ((m >> jj) << (jj+1)) | (m & ((1<<jj)-1));
                const int r1 = r0 | (1 << jj);
                bfly(v[r0], v[r1], tq[m << 4]);
            }
        }
        #pragma unroll
        for (int r = 0; r < 16; ++r)
            lq[(ebase + (r << 4)) ^ (r & 7)] = v[r];
    }
    __syncthreads();

    // ================= L2P3: stages 8..10 (strides 256,512,1024) + b2 + store =============
    {
        const int q  = t >> 8;
        const int b  = t & 255;
        const int sw = (b >> 4) & 7;
        float4* lq = lds + q*4096;
        float4 v[8];
        #pragma unroll
        for (int r = 0; r < 8; ++r) v[r] = lq[(b + (r<<8)) ^ sw];   // p = b + r*256
        #pragma unroll
        for (int jj = 0; jj < 3; ++jj) {
            const float4* tq = tw2q + (8+jj)*1024 + b;  // tidx = b + m*256
            #pragma unroll
            for (int m = 0; m < 4; ++m) {
                const int r0 = ((m >> jj) << (jj+1)) | (m & ((1<<jj)-1));
                const int r1 = r0 | (1 << jj);
                bfly(v[r0], v[r1], tq[m << 8]);
            }
        }
        // out = first 1024 elements (r<4) + b2; coalesced across b
        float* ob = out + (size_t)(row0 + q*4) * 1024 + b;
        #pragma unroll
        for (int r = 0; r < 4; ++r) {
            const float bb = b2[b + (r<<8)];
            ob[0*1024 + (r<<8)] = v[r].x + bb;
            ob[1*1024 + (r<<8)] = v[r].y + bb;
            ob[2*1024 + (r<<8)] = v[r].z + bb;
            ob[3*1024 + (r<<8)] = v[r].w + bb;
        }
    }
}

extern "C" void kernel_launch(void* const* d_in, const int* in_sizes, int n_in,
                              void* d_out, int out_size, void* d_ws, size_t ws_size,
                              hipStream_t stream) {
    const float* x   = (const float*)d_in[0];
    const float* tw1 = (const float*)d_in[1];
    const float* b1  = (const float*)d_in[2];
    const float* tw2 = (const float*)d_in[3];
    const float* b2  = (const float*)d_in[4];
    float* outp = (float*)d_out;

    // 128 KiB dynamic LDS (> 64 KiB default) — opt in every call (cheap, idempotent)
    (void)hipFuncSetAttribute((const void*)glu_butterfly,
                              hipFuncAttributeMaxDynamicSharedMemorySize, 131072);
    glu_butterfly<<<NBLK, NTHR, 131072, stream>>>(x, tw1, b1, tw2, b2, outp);
}

// Round 2
// 210.043 us; speedup vs baseline: 1.3903x; 1.3903x over previous
//
#include <hip/hip_runtime.h>
#include <cstdint>

// Fused butterfly-GLU-butterfly, round 2.
// 16384 rows; L1: 4 stacks x n=1024 (10 stages) + bias; GLU; L2: n=2048 (11 stages) + bias.
// Block = 4 rows (one float4-packed "quad"), 512 threads, 64 KiB LDS -> 2 blocks/CU
// = 16 waves/CU (round 1 was 128 KiB -> 1 block -> 8 waves, latency-bound at 22% issue).
// LDS element = float4 of 4 rows at one butterfly position; XOR swizzle e^((e>>4)&7)
// spreads power-of-2 strides across banks; every LDS access is ds_*_b128.
// 9 passes: L1 s0-2 (from global), s3-5, s6-8, [s9+bias+GLU+L2 s0], L2 s1-2, s3-4,
// s5-6, s7-8, s9-10+bias+store. All L2 passes are in-place (each thread owns its slots).

#define NTHR 512
#define NBLK 4096   // 4096 * 4 rows = 16384

__device__ __forceinline__ float sigmf(float g) {
    return __builtin_amdgcn_rcpf(1.0f + __expf(-g));
}

__device__ __forceinline__ int swz(int e) { return e ^ ((e >> 4) & 7); }

// a' = t00*a + t01*b ; b' = t10*a + t11*b ; t=(t00,t01,t10,t11)
__device__ __forceinline__ void bfly(float4& a, float4& b, const float4 t) {
    float4 n0, n1;
    n0.x = fmaf(t.x, a.x, t.y * b.x);
    n0.y = fmaf(t.x, a.y, t.y * b.y);
    n0.z = fmaf(t.x, a.z, t.y * b.z);
    n0.w = fmaf(t.x, a.w, t.y * b.w);
    n1.x = fmaf(t.z, a.x, t.w * b.x);
    n1.y = fmaf(t.z, a.y, t.w * b.y);
    n1.z = fmaf(t.z, a.z, t.w * b.z);
    n1.w = fmaf(t.z, a.w, t.w * b.w);
    a = n0; b = n1;
}

// L2 2-stage pass: stages K and K+1, thread owns r-bits {K,K+1}; in-place in lds[0,2048).
template<int K>
__device__ __forceinline__ void l2pass(float4* lds, const float4* tw2q, int t) {
    const int low   = t & ((1 << K) - 1);
    const int hi    = t >> K;
    const int pbase = low | (hi << (K + 2));
    float4 tws[2][2];
    #pragma unroll
    for (int jj = 0; jj < 2; ++jj) {
        const float4* tq = tw2q + (K + jj) * 1024 + (low | (hi << (K + 1)));
        tws[jj][0] = tq[0];
        tws[jj][1] = tq[1 << K];
    }
    float4 v[4];
    #pragma unroll
    for (int r = 0; r < 4; ++r) v[r] = lds[swz(pbase | (r << K))];
    bfly(v[0], v[1], tws[0][0]);   // stage K
    bfly(v[2], v[3], tws[0][1]);
    bfly(v[0], v[2], tws[1][0]);   // stage K+1
    bfly(v[1], v[3], tws[1][1]);
    #pragma unroll
    for (int r = 0; r < 4; ++r) lds[swz(pbase | (r << K))] = v[r];
}

__global__ __launch_bounds__(NTHR, 4) void glu_butterfly(
    const float* __restrict__ x, const float* __restrict__ tw1,
    const float* __restrict__ b1, const float* __restrict__ tw2,
    const float* __restrict__ b2, float* __restrict__ out)
{
    extern __shared__ float4 lds[];   // 4096 float4 = 65536 B
    const int t    = threadIdx.x;
    const int row0 = blockIdx.x * 4;
    const float4* tw1q = (const float4*)tw1;  // (4,10,512,2,2): (s*10+j)*512 + tidx
    const float4* tw2q = (const float4*)tw2;  // (1,11,1024,2,2): j*1024 + tidx

    // ---- P1: global x -> L1 stages 0..2 -> LDS -----------------------------------
    {
        const int s = t >> 7;        // stack
        const int c = t & 127;       // 8-element chunk within stack
        float4 d[8];
        float* dp = (float*)d;
        const float* xb = x + (size_t)row0 * 1024 + c * 8;   // same data for all stacks
        #pragma unroll
        for (int rr = 0; rr < 4; ++rr) {
            const float4* xp = (const float4*)(xb + rr * 1024);
            float4 v0 = xp[0], v1 = xp[1];
            dp[0*4+rr] = v0.x; dp[1*4+rr] = v0.y; dp[2*4+rr] = v0.z; dp[3*4+rr] = v0.w;
            dp[4*4+rr] = v1.x; dp[5*4+rr] = v1.y; dp[6*4+rr] = v1.z; dp[7*4+rr] = v1.w;
        }
        #pragma unroll
        for (int j = 0; j < 3; ++j) {
            const float4* tq = tw1q + (s * 10 + j) * 512 + c * 4;
            #pragma unroll
            for (int m = 0; m < 4; ++m) {
                const int i0 = ((m >> j) << (j + 1)) | (m & ((1 << j) - 1));
                bfly(d[i0], d[i0 | (1 << j)], tq[m]);
            }
        }
        const int ebase = s * 1024 + c * 8;
        #pragma unroll
        for (int k = 0; k < 8; ++k) lds[swz(ebase + k)] = d[k];
    }
    __syncthreads();

    // ---- P2: L1 stages 3..5 (r-bits 3..5) ----------------------------------------
    {
        const int low = t & 7, hi = t >> 3;     // hi: p bits 6..11
        const int s = hi >> 4;
        const int pbase = low | (hi << 6);
        float4 tws[3][4];
        #pragma unroll
        for (int jj = 0; jj < 3; ++jj) {
            const float4* tq = tw1q + (s * 10 + 3 + jj) * 512 + (low | ((hi & 15) << 5));
            #pragma unroll
            for (int m = 0; m < 4; ++m) tws[jj][m] = tq[m << 3];
        }
        float4 v[8];
        #pragma unroll
        for (int r = 0; r < 8; ++r) v[r] = lds[swz(pbase | (r << 3))];
        #pragma unroll
        for (int jj = 0; jj < 3; ++jj) {
            #pragma unroll
            for (int m = 0; m < 4; ++m) {
                const int r0 = ((m >> jj) << (jj + 1)) | (m & ((1 << jj) - 1));
                bfly(v[r0], v[r0 | (1 << jj)], tws[jj][m]);
            }
        }
        #pragma unroll
        for (int r = 0; r < 8; ++r) lds[swz(pbase | (r << 3))] = v[r];
    }
    __syncthreads();

    // ---- P3: L1 stages 6..8 (r-bits 6..8) ----------------------------------------
    {
        const int low = t & 63, hi = t >> 6;    // hi: p bits 9..11
        const int s = hi >> 1;
        const int pbase = low | (hi << 9);
        float4 tws[3][4];
        #pragma unroll
        for (int jj = 0; jj < 3; ++jj) {
            const float4* tq = tw1q + (s * 10 + 6 + jj) * 512 + (low | ((hi & 1) << 8));
            #pragma unroll
            for (int m = 0; m < 4; ++m) tws[jj][m] = tq[m << 6];
        }
        float4 v[8];
        #pragma unroll
        for (int r = 0; r < 8; ++r) v[r] = lds[swz(pbase | (r << 6))];
        #pragma unroll
        for (int jj = 0; jj < 3; ++jj) {
            #pragma unroll
            for (int m = 0; m < 4; ++m) {
                const int r0 = ((m >> jj) << (jj + 1)) | (m & ((1 << jj) - 1));
                bfly(v[r0], v[r0 | (1 << jj)], tws[jj][m]);
            }
        }
        #pragma unroll
        for (int r = 0; r < 8; ++r) lds[swz(pbase | (r << 6))] = v[r];
    }
    __syncthreads();

    // ---- P4: L1 stage 9 + bias b1 + GLU + L2 stage 0 -> u in lds[0,2048) ---------
    {
        const int t8 = t & 255, th = t >> 8;    // th = p bit 10
        // p(a,b,c) = (t8<<1) | a | (b<<9) | (th<<10) | (c<<11); d idx = (c<<2)|(b<<1)|a
        float4 d[8];
        #pragma unroll
        for (int c = 0; c < 2; ++c)
        #pragma unroll
        for (int b = 0; b < 2; ++b)
        #pragma unroll
        for (int a = 0; a < 2; ++a) {
            const int e = (t8 << 1) | a | (b << 9) | (th << 10) | (c << 11);
            d[(c << 2) | (b << 1) | a] = lds[swz(e)];
        }
        // L1 stage 9: pairs differ in b; twiddle tidx = (t8<<1)|a, stack s = th|(c<<1)
        #pragma unroll
        for (int c = 0; c < 2; ++c)
        #pragma unroll
        for (int a = 0; a < 2; ++a) {
            const float4 tw9 = tw1q[((th | (c << 1)) * 10 + 9) * 512 + ((t8 << 1) | a)];
            bfly(d[(c << 2) | a], d[(c << 2) | 2 | a], tw9);
        }
        // bias b1[s*1024 + w], w = (t8<<1)|a|(b<<9)
        #pragma unroll
        for (int c = 0; c < 2; ++c)
        #pragma unroll
        for (int b = 0; b < 2; ++b)
        #pragma unroll
        for (int a = 0; a < 2; ++a) {
            const float bb = b1[(th | (c << 1)) * 1024 + ((t8 << 1) | a | (b << 9))];
            float4& dv = d[(c << 2) | (b << 1) | a];
            dv.x += bb; dv.y += bb; dv.z += bb; dv.w += bb;
        }
        // GLU: u = d[c=0] * sigmoid(d[c=1])
        float4 u[4];
        #pragma unroll
        for (int i = 0; i < 4; ++i) {
            const float4 av = d[i], gv = d[4 | i];
            u[i].x = av.x * sigmf(gv.x);
            u[i].y = av.y * sigmf(gv.y);
            u[i].z = av.z * sigmf(gv.z);
            u[i].w = av.w * sigmf(gv.w);
        }
        // L2 stage 0: pairs differ in a; tidx = t8 | (b<<8) | (th<<9)
        #pragma unroll
        for (int b = 0; b < 2; ++b) {
            const float4 tw0 = tw2q[t8 | (b << 8) | (th << 9)];
            bfly(u[b << 1], u[(b << 1) | 1], tw0);
        }
        // write u at u_idx = (t8<<1)|a|(b<<9)|(th<<10)  (own slots -> in-place safe)
        #pragma unroll
        for (int b = 0; b < 2; ++b)
        #pragma unroll
        for (int a = 0; a < 2; ++a) {
            const int e = (t8 << 1) | a | (b << 9) | (th << 10);
            lds[swz(e)] = u[(b << 1) | a];
        }
    }
    __syncthreads();

    // ---- L2 stages 1..8: four in-place 2-stage passes ----------------------------
    l2pass<1>(lds, tw2q, t); __syncthreads();
    l2pass<3>(lds, tw2q, t); __syncthreads();
    l2pass<5>(lds, tw2q, t); __syncthreads();
    l2pass<7>(lds, tw2q, t); __syncthreads();

    // ---- P9: L2 stages 9,10 + bias b2 + store ------------------------------------
    {
        float4 v[4];
        #pragma unroll
        for (int r = 0; r < 4; ++r) v[r] = lds[swz(t | (r << 9))];
        // stage 9 (pairs r-bit0), tidx = t | (m<<9)
        bfly(v[0], v[1], tw2q[9 * 1024 + t]);
        bfly(v[2], v[3], tw2q[9 * 1024 + (t | 512)]);
        // stage 10 (pairs r-bit1), tidx = t | (m<<9)
        bfly(v[0], v[2], tw2q[10 * 1024 + t]);
        bfly(v[1], v[3], tw2q[10 * 1024 + (t | 512)]);
        // keep p < 1024 (r in {0,1}); out[(row0+rr)*1024 + p] = v + b2[p]
        #pragma unroll
        for (int r = 0; r < 2; ++r) {
            const int p = t | (r << 9);
            const float bb = b2[p];
            float* ob = out + (size_t)row0 * 1024 + p;
            ob[0]    = v[r].x + bb;
            ob[1024] = v[r].y + bb;
            ob[2048] = v[r].z + bb;
            ob[3072] = v[r].w + bb;
        }
    }
}

extern "C" void kernel_launch(void* const* d_in, const int* in_sizes, int n_in,
                              void* d_out, int out_size, void* d_ws, size_t ws_size,
                              hipStream_t stream) {
    const float* x   = (const float*)d_in[0];
    const float* tw1 = (const float*)d_in[1];
    const float* b1  = (const float*)d_in[2];
    const float* tw2 = (const float*)d_in[3];
    const float* b2  = (const float*)d_in[4];
    float* outp = (float*)d_out;

    (void)hipFuncSetAttribute((const void*)glu_butterfly,
                              hipFuncAttributeMaxDynamicSharedMemorySize, 65536);
    glu_butterfly<<<NBLK, NTHR, 65536, stream>>>(x, tw1, b1, tw2, b2, outp);
}

// Round 3
// 189.581 us; speedup vs baseline: 1.5404x; 1.1079x over previous
//
#include <hip/hip_runtime.h>
#include <cstdint>

// Fused butterfly-GLU-butterfly, round 3.
// Round-2 post-mortem: VALUBusy(43%) ~= Occupancy(40%) -> issue-limited by waves;
// ~2170 VALU instr/thread of which only ~990 are FMA payload. Fix: 8 rows/block
// (2048 blocks) with intermediates stored bf16x8 (16 B/position) -> LDS stays
// 64 KiB and every pass's overhead is amortized over 2x rows. Compute is fp32 in
// registers (ext_vector v4f to enable v_pk_fma_f32); bf16 quantization only at
// pass boundaries (RNE-ish via +0x8000 + v_perm pack). Indexing identical to the
// verified round-2 kernel.

#define NTHR 512
#define NBLK 2048   // 2048 * 8 rows = 16384

typedef float        v4f __attribute__((ext_vector_type(4)));
typedef unsigned int u4i __attribute__((ext_vector_type(4)));

struct F8 { v4f lo, hi; };   // 8 rows of one butterfly position, fp32

__device__ __forceinline__ float sigmf(float g) {
    return __builtin_amdgcn_rcpf(1.0f + __expf(-g));
}

__device__ __forceinline__ v4f sig4(v4f g) {
    v4f r;
    r.x = sigmf(g.x); r.y = sigmf(g.y); r.z = sigmf(g.z); r.w = sigmf(g.w);
    return r;
}

__device__ __forceinline__ int swz(int e) { return e ^ ((e >> 4) & 7); }

// pack two fp32 -> bf16x2 (a low16, b high16), round-to-nearest(ties away)
__device__ __forceinline__ unsigned pk2(float a, float b) {
    unsigned ua = __float_as_uint(a) + 0x8000u;
    unsigned ub = __float_as_uint(b) + 0x8000u;
    return __builtin_amdgcn_perm(ub, ua, 0x07060302u);  // {ub.hi16, ua.hi16}
}

__device__ __forceinline__ u4i packF8(const F8& v) {
    u4i r;
    r.x = pk2(v.lo.x, v.lo.y);
    r.y = pk2(v.lo.z, v.lo.w);
    r.z = pk2(v.hi.x, v.hi.y);
    r.w = pk2(v.hi.z, v.hi.w);
    return r;
}

__device__ __forceinline__ F8 unpackF8(u4i u) {
    F8 v;
    v.lo.x = __uint_as_float(u.x << 16);
    v.lo.y = __uint_as_float(u.x & 0xffff0000u);
    v.lo.z = __uint_as_float(u.y << 16);
    v.lo.w = __uint_as_float(u.y & 0xffff0000u);
    v.hi.x = __uint_as_float(u.z << 16);
    v.hi.y = __uint_as_float(u.z & 0xffff0000u);
    v.hi.z = __uint_as_float(u.w << 16);
    v.hi.w = __uint_as_float(u.w & 0xffff0000u);
    return v;
}

// a' = t00*a + t01*b ; b' = t10*a + t11*b on 8 packed rows
__device__ __forceinline__ void bfly(F8& a, F8& b, const v4f t) {
    v4f n0l = t.x * a.lo + t.y * b.lo;
    v4f n0h = t.x * a.hi + t.y * b.hi;
    v4f n1l = t.z * a.lo + t.w * b.lo;
    v4f n1h = t.z * a.hi + t.w * b.hi;
    a.lo = n0l; a.hi = n0h; b.lo = n1l; b.hi = n1h;
}

// L2 2-stage pass: stages K,K+1; in-place on lds[0,2048)
template<int K>
__device__ __forceinline__ void l2pass(u4i* lds, const v4f* tw2q, int t) {
    const int low   = t & ((1 << K) - 1);
    const int hi    = t >> K;
    const int pbase = low | (hi << (K + 2));
    F8 v[4];
    #pragma unroll
    for (int r = 0; r < 4; ++r) v[r] = unpackF8(lds[swz(pbase | (r << K))]);
    {
        const v4f* tq = tw2q + K * 1024 + (low | (hi << (K + 1)));
        bfly(v[0], v[1], tq[0]);
        bfly(v[2], v[3], tq[1 << K]);
    }
    {
        const v4f* tq = tw2q + (K + 1) * 1024 + (low | (hi << (K + 1)));
        bfly(v[0], v[2], tq[0]);
        bfly(v[1], v[3], tq[1 << K]);
    }
    #pragma unroll
    for (int r = 0; r < 4; ++r) lds[swz(pbase | (r << K))] = packF8(v[r]);
}

__global__ __launch_bounds__(NTHR, 4) void glu_butterfly(
    const float* __restrict__ x, const float* __restrict__ tw1,
    const float* __restrict__ b1, const float* __restrict__ tw2,
    const float* __restrict__ b2, float* __restrict__ out)
{
    extern __shared__ u4i lds[];      // 4096 * 16 B = 65536 B
    const int t    = threadIdx.x;
    const int row0 = blockIdx.x * 8;  // 8 rows per block
    const v4f* tw1q = (const v4f*)tw1;  // (4,10,512,2,2): (s*10+j)*512 + tidx
    const v4f* tw2q = (const v4f*)tw2;  // (1,11,1024,2,2): j*1024 + tidx

    // ---- P1: global x -> L1 stages 0..2 -> LDS -----------------------------------
    {
        const int s = t >> 7;        // stack
        const int c = t & 127;       // 8-position chunk within stack
        float xs[8][8];
        const float* xb = x + (size_t)row0 * 1024 + c * 8;
        #pragma unroll
        for (int rr = 0; rr < 8; ++rr) {
            const v4f* xp = (const v4f*)(xb + rr * 1024);
            v4f a = xp[0], b = xp[1];
            xs[rr][0] = a.x; xs[rr][1] = a.y; xs[rr][2] = a.z; xs[rr][3] = a.w;
            xs[rr][4] = b.x; xs[rr][5] = b.y; xs[rr][6] = b.z; xs[rr][7] = b.w;
        }
        F8 d[8];
        #pragma unroll
        for (int k = 0; k < 8; ++k) {
            d[k].lo = (v4f){xs[0][k], xs[1][k], xs[2][k], xs[3][k]};
            d[k].hi = (v4f){xs[4][k], xs[5][k], xs[6][k], xs[7][k]};
        }
        #pragma unroll
        for (int j = 0; j < 3; ++j) {
            const v4f* tq = tw1q + (s * 10 + j) * 512 + c * 4;
            #pragma unroll
            for (int m = 0; m < 4; ++m) {
                const int i0 = ((m >> j) << (j + 1)) | (m & ((1 << j) - 1));
                bfly(d[i0], d[i0 | (1 << j)], tq[m]);
            }
        }
        const int ebase = s * 1024 + c * 8;
        #pragma unroll
        for (int k = 0; k < 8; ++k) lds[swz(ebase + k)] = packF8(d[k]);
    }
    __syncthreads();

    // ---- P2: L1 stages 3..5 (r-bits 3..5) ----------------------------------------
    {
        const int low = t & 7, hi = t >> 3;     // hi: p bits 6..11
        const int s = hi >> 4;
        const int pbase = low | (hi << 6);
        F8 v[8];
        #pragma unroll
        for (int r = 0; r < 8; ++r) v[r] = unpackF8(lds[swz(pbase | (r << 3))]);
        #pragma unroll
        for (int jj = 0; jj < 3; ++jj) {
            const v4f* tq = tw1q + (s * 10 + 3 + jj) * 512 + (low | ((hi & 15) << 5));
            #pragma unroll
            for (int m = 0; m < 4; ++m) {
                const int r0 = ((m >> jj) << (jj + 1)) | (m & ((1 << jj) - 1));
                bfly(v[r0], v[r0 | (1 << jj)], tq[m << 3]);
            }
        }
        #pragma unroll
        for (int r = 0; r < 8; ++r) lds[swz(pbase | (r << 3))] = packF8(v[r]);
    }
    __syncthreads();

    // ---- P3: L1 stages 6..8 (r-bits 6..8) ----------------------------------------
    {
        const int low = t & 63, hi = t >> 6;    // hi: p bits 9..11
        const int s = hi >> 1;
        const int pbase = low | (hi << 9);
        F8 v[8];
        #pragma unroll
        for (int r = 0; r < 8; ++r) v[r] = unpackF8(lds[swz(pbase | (r << 6))]);
        #pragma unroll
        for (int jj = 0; jj < 3; ++jj) {
            const v4f* tq = tw1q + (s * 10 + 6 + jj) * 512 + (low | ((hi & 1) << 8));
            #pragma unroll
            for (int m = 0; m < 4; ++m) {
                const int r0 = ((m >> jj) << (jj + 1)) | (m & ((1 << jj) - 1));
                bfly(v[r0], v[r0 | (1 << jj)], tq[m << 6]);
            }
        }
        #pragma unroll
        for (int r = 0; r < 8; ++r) lds[swz(pbase | (r << 6))] = packF8(v[r]);
    }
    __syncthreads();

    // ---- P4: L1 stage 9 + bias b1 + GLU + L2 stage 0 -> u in lds ------------------
    {
        const int t8 = t & 255, th = t >> 8;    // th = p bit 10
        // p(a,b,c) = (t8<<1)|a|(b<<9)|(th<<10)|(c<<11); d idx = (c<<2)|(b<<1)|a
        F8 d[8];
        #pragma unroll
        for (int c = 0; c < 2; ++c)
        #pragma unroll
        for (int b = 0; b < 2; ++b)
        #pragma unroll
        for (int a = 0; a < 2; ++a) {
            const int e = (t8 << 1) | a | (b << 9) | (th << 10) | (c << 11);
            d[(c << 2) | (b << 1) | a] = unpackF8(lds[swz(e)]);
        }
        // L1 stage 9: pairs differ in b; tidx = (t8<<1)|a, stack s = th|(c<<1)
        #pragma unroll
        for (int c = 0; c < 2; ++c)
        #pragma unroll
        for (int a = 0; a < 2; ++a) {
            const v4f tw9 = tw1q[((th | (c << 1)) * 10 + 9) * 512 + ((t8 << 1) | a)];
            bfly(d[(c << 2) | a], d[(c << 2) | 2 | a], tw9);
        }
        // bias b1[s*1024 + w], w = (t8<<1)|a|(b<<9)
        #pragma unroll
        for (int c = 0; c < 2; ++c)
        #pragma unroll
        for (int b = 0; b < 2; ++b)
        #pragma unroll
        for (int a = 0; a < 2; ++a) {
            const float bb = b1[(th | (c << 1)) * 1024 + ((t8 << 1) | a | (b << 9))];
            F8& dv = d[(c << 2) | (b << 1) | a];
            dv.lo += bb; dv.hi += bb;
        }
        // GLU: u = d[c=0] * sigmoid(d[c=1])
        F8 u[4];
        #pragma unroll
        for (int i = 0; i < 4; ++i) {
            u[i].lo = d[i].lo * sig4(d[4 | i].lo);
            u[i].hi = d[i].hi * sig4(d[4 | i].hi);
        }
        // L2 stage 0: pairs differ in a; tidx = t8|(b<<8)|(th<<9)
        #pragma unroll
        for (int b = 0; b < 2; ++b) {
            const v4f tw0 = tw2q[t8 | (b << 8) | (th << 9)];
            bfly(u[b << 1], u[(b << 1) | 1], tw0);
        }
        // write u at (t8<<1)|a|(b<<9)|(th<<10)  (slots this thread read; in-place safe)
        #pragma unroll
        for (int b = 0; b < 2; ++b)
        #pragma unroll
        for (int a = 0; a < 2; ++a) {
            const int e = (t8 << 1) | a | (b << 9) | (th << 10);
            lds[swz(e)] = packF8(u[(b << 1) | a]);
        }
    }
    __syncthreads();

    // ---- L2 stages 1..8: four in-place 2-stage passes ----------------------------
    l2pass<1>(lds, tw2q, t); __syncthreads();
    l2pass<3>(lds, tw2q, t); __syncthreads();
    l2pass<5>(lds, tw2q, t); __syncthreads();
    l2pass<7>(lds, tw2q, t); __syncthreads();

    // ---- P9: L2 stages 9,10 + bias b2 + store ------------------------------------
    {
        F8 v[4];
        #pragma unroll
        for (int r = 0; r < 4; ++r) v[r] = unpackF8(lds[swz(t | (r << 9))]);
        bfly(v[0], v[1], tw2q[9 * 1024 + t]);          // stage 9
        bfly(v[2], v[3], tw2q[9 * 1024 + (t | 512)]);
        bfly(v[0], v[2], tw2q[10 * 1024 + t]);         // stage 10
        bfly(v[1], v[3], tw2q[10 * 1024 + (t | 512)]);
        // keep p < 1024 (r in {0,1}); out[(row0+rr)*1024 + p] = v + b2[p]
        #pragma unroll
        for (int r = 0; r < 2; ++r) {
            const int p = t | (r << 9);
            const float bb = b2[p];
            float* ob = out + (size_t)row0 * 1024 + p;
            ob[0*1024] = v[r].lo.x + bb;
            ob[1*1024] = v[r].lo.y + bb;
            ob[2*1024] = v[r].lo.z + bb;
            ob[3*1024] = v[r].lo.w + bb;
            ob[4*1024] = v[r].hi.x + bb;
            ob[5*1024] = v[r].hi.y + bb;
            ob[6*1024] = v[r].hi.z + bb;
            ob[7*1024] = v[r].hi.w + bb;
        }
    }
}

extern "C" void kernel_launch(void* const* d_in, const int* in_sizes, int n_in,
                              void* d_out, int out_size, void* d_ws, size_t ws_size,
                              hipStream_t stream) {
    const float* x   = (const float*)d_in[0];
    const float* tw1 = (const float*)d_in[1];
    const float* b1  = (const float*)d_in[2];
    const float* tw2 = (const float*)d_in[3];
    const float* b2  = (const float*)d_in[4];
    float* outp = (float*)d_out;

    (void)hipFuncSetAttribute((const void*)glu_butterfly,
                              hipFuncAttributeMaxDynamicSharedMemorySize, 65536);
    glu_butterfly<<<NBLK, NTHR, 65536, stream>>>(x, tw1, b1, tw2, b2, outp);
}